// Round 1
// baseline (616.346 us; speedup 1.0000x reference)
//
#include <hip/hip_runtime.h>
#include <stdint.h>

#define NROWS 8192
#define MROWS 65536
#define DDIM  512
#define BK    64
#define CT_PER_BLOCK 16
#define NBLOCKS 2048   // (NROWS/128) * (MROWS/(128*CT_PER_BLOCK)) = 64*32

typedef __attribute__((ext_vector_type(4))) float f32x4;
typedef __attribute__((ext_vector_type(8))) short short8;
typedef unsigned short ushort_t;
typedef unsigned int   uint_t;

// Round-to-nearest-even fp32 -> bf16 (bit manipulation; used consistently in
// norms, convert, and fallback staging so cross-term and norms match).
__device__ __forceinline__ ushort_t f2bf(float x) {
    uint_t u = __float_as_uint(x);
    u += 0x7fffu + ((u >> 16) & 1u);
    return (ushort_t)(u >> 16);
}
__device__ __forceinline__ float bf2f(ushort_t b) {
    return __uint_as_float(((uint_t)b) << 16);
}

__device__ __forceinline__ void gll16(const void* g, void* l) {
    __builtin_amdgcn_global_load_lds((__attribute__((address_space(1))) void*)g,
                                     (__attribute__((address_space(3))) void*)l,
                                     16, 0, 0);
}

// ---- init min buffer to +inf -------------------------------------------------
__global__ void init_minsq(uint_t* minsq) {
    int i = blockIdx.x * 256 + threadIdx.x;
    if (i < NROWS) minsq[i] = 0x7f800000u;  // +inf
}

// ---- row norms of bf16-rounded inputs (one wave per row) ---------------------
__global__ void norms_kernel(const float* __restrict__ emb, const float* __restrict__ mem,
                             float* __restrict__ xsq, float* __restrict__ msq) {
    int row  = blockIdx.x * 4 + (threadIdx.x >> 6);
    int lane = threadIdx.x & 63;
    const float* src;
    float* dst;
    if (row < NROWS) { src = emb + (size_t)row * DDIM;           dst = xsq + row; }
    else             { src = mem + (size_t)(row - NROWS) * DDIM; dst = msq + (row - NROWS); }
    float4 f0 = *(const float4*)(src + lane * 8);
    float4 f1 = *(const float4*)(src + lane * 8 + 4);
    float s = 0.f, v;
    v = bf2f(f2bf(f0.x)); s += v * v;
    v = bf2f(f2bf(f0.y)); s += v * v;
    v = bf2f(f2bf(f0.z)); s += v * v;
    v = bf2f(f2bf(f0.w)); s += v * v;
    v = bf2f(f2bf(f1.x)); s += v * v;
    v = bf2f(f2bf(f1.y)); s += v * v;
    v = bf2f(f2bf(f1.z)); s += v * v;
    v = bf2f(f2bf(f1.w)); s += v * v;
    #pragma unroll
    for (int o = 1; o < 64; o <<= 1) s += __shfl_xor(s, o);
    if (lane == 0) *dst = s;
}

// ---- fp32 -> bf16 copy, pre-swizzled so linear global_load_lds yields the
//      XOR-swizzled LDS image: stored chunk cc = original chunk (cc ^ (row&7)),
//      chunks are 16B (8 bf16) within each 64-element K segment. -------------
__global__ void convert_kernel(const float* __restrict__ emb, const float* __restrict__ mem,
                               ushort_t* __restrict__ Abf, ushort_t* __restrict__ Bbf) {
    unsigned gid = blockIdx.x * 256 + threadIdx.x;   // one 16B chunk per thread
    unsigned row = gid >> 6;
    unsigned within = gid & 63u;
    unsigned seg = within >> 3, cc = within & 7u;
    const float* src; ushort_t* dst; unsigned r;
    if (row < NROWS) { r = row;         src = emb + (size_t)r * DDIM; dst = Abf + (size_t)r * DDIM; }
    else             { r = row - NROWS; src = mem + (size_t)r * DDIM; dst = Bbf + (size_t)r * DDIM; }
    unsigned scc = cc ^ (r & 7u);
    const float4* s4 = (const float4*)(src + seg * 64 + scc * 8);
    float4 a = s4[0], b = s4[1];
    uint4 w;
    w.x = (uint_t)f2bf(a.x) | ((uint_t)f2bf(a.y) << 16);
    w.y = (uint_t)f2bf(a.z) | ((uint_t)f2bf(a.w) << 16);
    w.z = (uint_t)f2bf(b.x) | ((uint_t)f2bf(b.y) << 16);
    w.w = (uint_t)f2bf(b.z) | ((uint_t)f2bf(b.w) << 16);
    *(uint4*)(dst + seg * 64 + cc * 8) = w;
}

// ---- fallback reg-staging helpers (fp32 global -> bf16 LDS, same swizzle) ---
__device__ __forceinline__ void stage_load(const float* __restrict__ emb,
                                           const float* __restrict__ mem,
                                           size_t r0, size_t c0, int ks,
                                           float4* ra, float4* rb, int tid) {
    #pragma unroll
    for (int p = 0; p < 4; ++p) {
        int row = p * 32 + (tid >> 3);
        int c   = (tid & 7) * 8;
        const float* sa = emb + (r0 + row) * DDIM + ks * BK + c;
        const float* sb = mem + (c0 + row) * DDIM + ks * BK + c;
        ra[2*p]   = *(const float4*)sa;
        ra[2*p+1] = *(const float4*)(sa + 4);
        rb[2*p]   = *(const float4*)sb;
        rb[2*p+1] = *(const float4*)(sb + 4);
    }
}

__device__ __forceinline__ void stage_write(ushort_t* Ab, ushort_t* Bb,
                                            const float4* ra, const float4* rb, int tid) {
    #pragma unroll
    for (int p = 0; p < 4; ++p) {
        int row = p * 32 + (tid >> 3);
        int ccs = (tid & 7) ^ (row & 7);
        uint4 wa, wb;
        wa.x = (uint_t)f2bf(ra[2*p].x)   | ((uint_t)f2bf(ra[2*p].y)   << 16);
        wa.y = (uint_t)f2bf(ra[2*p].z)   | ((uint_t)f2bf(ra[2*p].w)   << 16);
        wa.z = (uint_t)f2bf(ra[2*p+1].x) | ((uint_t)f2bf(ra[2*p+1].y) << 16);
        wa.w = (uint_t)f2bf(ra[2*p+1].z) | ((uint_t)f2bf(ra[2*p+1].w) << 16);
        wb.x = (uint_t)f2bf(rb[2*p].x)   | ((uint_t)f2bf(rb[2*p].y)   << 16);
        wb.y = (uint_t)f2bf(rb[2*p].z)   | ((uint_t)f2bf(rb[2*p].w)   << 16);
        wb.z = (uint_t)f2bf(rb[2*p+1].x) | ((uint_t)f2bf(rb[2*p+1].y) << 16);
        wb.w = (uint_t)f2bf(rb[2*p+1].z) | ((uint_t)f2bf(rb[2*p+1].w) << 16);
        *(uint4*)&Ab[row * BK + ccs * 8] = wa;
        *(uint4*)&Bb[row * BK + ccs * 8] = wb;
    }
}

// ---- fused GEMM(cross) + per-row running-min kernel --------------------------
// 128x128 tile, 4 waves (2x2), mfma_f32_16x16x32_bf16, BK=64, single LDS buffer,
// 2 barriers/K-step (m97 structure). Block loops over 16 col-tiles.
template<bool PRECONV>
__global__ __launch_bounds__(256, 2) void gemm_min_kernel(
    const float* __restrict__ emb, const float* __restrict__ mem,
    const ushort_t* __restrict__ Abf, const ushort_t* __restrict__ Bbf,
    const float* __restrict__ xsq, const float* __restrict__ msq,
    uint_t* __restrict__ minsq)
{
    __shared__ alignas(16) ushort_t Ab[128 * BK];  // 16 KiB
    __shared__ alignas(16) ushort_t Bb[128 * BK];  // 16 KiB

    const int tid  = threadIdx.x;
    const int lane = tid & 63;
    const int wave = tid >> 6;
    const int wm = wave >> 1, wn = wave & 1;

    // bijective XCD-chunked swizzle (2048 % 8 == 0)
    unsigned wg  = blockIdx.x;
    unsigned swz = (wg & 7u) * (NBLOCKS / 8) + (wg >> 3);
    const unsigned rt = swz & 63u;   // row tile   (N/128 = 64)
    const unsigned cg = swz >> 6;    // col group  (32 groups x 16 tiles)
    const size_t r0 = (size_t)rt * 128;

    float runmin[4][4];
    #pragma unroll
    for (int m = 0; m < 4; ++m)
        #pragma unroll
        for (int j = 0; j < 4; ++j) runmin[m][j] = 3.0e38f;

    float4 ra[8], rb[8];  // fallback staging regs (DCE'd in PRECONV)

    for (int ct = 0; ct < CT_PER_BLOCK; ++ct) {
        const size_t c0 = ((size_t)cg * CT_PER_BLOCK + ct) * 128;

        f32x4 acc[4][4] = {};

        if constexpr (!PRECONV) {
            stage_load(emb, mem, r0, c0, 0, ra, rb, tid);
        }

        for (int ks = 0; ks < DDIM / BK; ++ks) {
            if constexpr (PRECONV) {
                // width-16 async global->LDS; LDS dest wave-uniform, HW adds lane*16
                #pragma unroll
                for (int i = 0; i < 4; ++i) {
                    int t     = (i * 4 + wave) * 1024 + lane * 16;  // byte within 16KB tile
                    int rowi  = t >> 7;
                    int inrow = t & 127;
                    const char* gA = (const char*)Abf + (r0 + rowi) * 1024 + (size_t)ks * 128 + inrow;
                    const char* gB = (const char*)Bbf + (c0 + rowi) * 1024 + (size_t)ks * 128 + inrow;
                    gll16(gA, (char*)Ab + (i * 4 + wave) * 1024);
                    gll16(gB, (char*)Bb + (i * 4 + wave) * 1024);
                }
                __syncthreads();  // drains vmcnt -> tiles ready
            } else {
                __syncthreads();  // previous compute done reading LDS
                stage_write(Ab, Bb, ra, rb, tid);
                if (ks + 1 < DDIM / BK) stage_load(emb, mem, r0, c0, ks + 1, ra, rb, tid);
                __syncthreads();  // writes visible
            }

            #pragma unroll
            for (int kk = 0; kk < 2; ++kk) {
                short8 af[4], bfm[4];
                #pragma unroll
                for (int m = 0; m < 4; ++m) {
                    int r = wm * 64 + m * 16 + (lane & 15);
                    int c = ((kk * 4 + (lane >> 4)) ^ (r & 7)) * 8;
                    af[m] = *(const short8*)&Ab[r * BK + c];
                }
                #pragma unroll
                for (int n = 0; n < 4; ++n) {
                    int r = wn * 64 + n * 16 + (lane & 15);
                    int c = ((kk * 4 + (lane >> 4)) ^ (r & 7)) * 8;
                    bfm[n] = *(const short8*)&Bb[r * BK + c];
                }
                #pragma unroll
                for (int m = 0; m < 4; ++m)
                    #pragma unroll
                    for (int n = 0; n < 4; ++n)
                        acc[m][n] = __builtin_amdgcn_mfma_f32_16x16x32_bf16(af[m], bfm[n], acc[m][n], 0, 0, 0);
            }
            if constexpr (PRECONV) __syncthreads();  // reads done before next overwrite
        }

        // fold this col-tile into the running min: v = msq[c] - 2*cross
        float mc[4];
        #pragma unroll
        for (int n = 0; n < 4; ++n) mc[n] = msq[c0 + wn * 64 + n * 16 + (lane & 15)];
        #pragma unroll
        for (int m = 0; m < 4; ++m)
            #pragma unroll
            for (int n = 0; n < 4; ++n)
                #pragma unroll
                for (int j = 0; j < 4; ++j)
                    runmin[m][j] = fminf(runmin[m][j], fmaf(-2.f, acc[m][n][j], mc[n]));
    }

    // reduce over the 16 col-lanes, add row norm, clamp, merge via uint atomicMin
    #pragma unroll
    for (int m = 0; m < 4; ++m)
        #pragma unroll
        for (int j = 0; j < 4; ++j) {
            float v = runmin[m][j];
            v = fminf(v, __shfl_xor(v, 1));
            v = fminf(v, __shfl_xor(v, 2));
            v = fminf(v, __shfl_xor(v, 4));
            v = fminf(v, __shfl_xor(v, 8));
            if ((lane & 15) == 0) {
                int grow = (int)r0 + wm * 64 + m * 16 + (lane >> 4) * 4 + j;
                float d2 = fmaxf(v + xsq[grow], 0.f);
                atomicMin(&minsq[grow], __float_as_uint(d2));
            }
        }
}

// ---- final sqrt --------------------------------------------------------------
__global__ void finish_kernel(const uint_t* __restrict__ minsq, float* __restrict__ out) {
    int i = blockIdx.x * 256 + threadIdx.x;
    if (i < NROWS) out[i] = sqrtf(__uint_as_float(minsq[i]));
}

extern "C" void kernel_launch(void* const* d_in, const int* in_sizes, int n_in,
                              void* d_out, int out_size, void* d_ws, size_t ws_size,
                              hipStream_t stream) {
    const float* emb = (const float*)d_in[0];
    const float* mem = (const float*)d_in[1];
    float* out = (float*)d_out;

    char* ws = (char*)d_ws;
    float*  xsq   = (float*)ws;                          // 32 KiB
    float*  msq   = (float*)(ws + 32768);                // 256 KiB
    uint_t* minsq = (uint_t*)(ws + 32768 + 262144);      // 32 KiB
    ushort_t* Abf = (ushort_t*)(ws + 327680);            // 8 MiB
    ushort_t* Bbf = Abf + (size_t)NROWS * DDIM;          // 64 MiB
    const size_t NEED = 327680 + ((size_t)NROWS + MROWS) * DDIM * 2;

    init_minsq<<<(NROWS + 255) / 256, 256, 0, stream>>>(minsq);
    norms_kernel<<<(NROWS + MROWS) / 4, 256, 0, stream>>>(emb, mem, xsq, msq);
    if (ws_size >= NEED) {
        convert_kernel<<<((NROWS + MROWS) * 64) / 256, 256, 0, stream>>>(emb, mem, Abf, Bbf);
        gemm_min_kernel<true><<<NBLOCKS, 256, 0, stream>>>(emb, mem, Abf, Bbf, xsq, msq, minsq);
    } else {
        gemm_min_kernel<false><<<NBLOCKS, 256, 0, stream>>>(emb, mem, Abf, Bbf, xsq, msq, minsq);
    }
    finish_kernel<<<(NROWS + 255) / 256, 256, 0, stream>>>(minsq, out);
}

// Round 2
// 593.711 us; speedup vs baseline: 1.0381x; 1.0381x over previous
//
#include <hip/hip_runtime.h>
#include <stdint.h>

#define NROWS 8192
#define MROWS 65536
#define DDIM  512

// ---- 256x256-tile deep-pipelined kernel params ----
#define BM 256
#define BN 256
#define BKK 32
#define CT 8                      // col-tiles per block
#define KT_PER_CT (DDIM / BKK)    // 16
#define NT (CT * KT_PER_CT)       // 128 K-tiles per block
#define GRID_X ((NROWS / BM) * (MROWS / (BN * CT)))  // 32 * 32 = 1024

typedef __attribute__((ext_vector_type(4))) float f32x4;
typedef __attribute__((ext_vector_type(8))) short short8;
typedef unsigned short ushort_t;
typedef unsigned int   uint_t;

// Round-to-nearest-even fp32 -> bf16 (used consistently everywhere).
__device__ __forceinline__ ushort_t f2bf(float x) {
    uint_t u = __float_as_uint(x);
    u += 0x7fffu + ((u >> 16) & 1u);
    return (ushort_t)(u >> 16);
}
__device__ __forceinline__ float bf2f(ushort_t b) {
    return __uint_as_float(((uint_t)b) << 16);
}

__device__ __forceinline__ void gll16(const void* g, void* l) {
    __builtin_amdgcn_global_load_lds((__attribute__((address_space(1))) void*)g,
                                     (__attribute__((address_space(3))) void*)l,
                                     16, 0, 0);
}

#define SBAR()  __builtin_amdgcn_s_barrier()
#define SCHED0() __builtin_amdgcn_sched_barrier(0)

// ---- init min buffer to +inf -------------------------------------------------
__global__ void init_minsq(uint_t* minsq) {
    int i = blockIdx.x * 256 + threadIdx.x;
    if (i < NROWS) minsq[i] = 0x7f800000u;  // +inf
}

// ---- fused fp32->bf16 convert (pre-swizzled for BK=32 tiles) + row norms ----
// One thread per 16B output chunk; one wave == one row (64 chunks * 8 bf16).
// Swizzle: within each 32-element K-segment (4 chunks), stored chunk cc holds
// original chunk cc ^ ((row>>1)&3). Norm = sum over the wave of rounded vals^2.
__global__ void convert_norms(const float* __restrict__ emb, const float* __restrict__ mem,
                              ushort_t* __restrict__ Abf, ushort_t* __restrict__ Bbf,
                              float* __restrict__ xsq, float* __restrict__ msq) {
    unsigned gid = blockIdx.x * 256 + threadIdx.x;
    unsigned row = gid >> 6;
    unsigned within = gid & 63u;
    unsigned seg = within >> 2, cc = within & 3u;
    int lane = threadIdx.x & 63;
    const float* src; ushort_t* dst; float* nrm; unsigned r;
    if (row < NROWS) { r = row;         src = emb + (size_t)r * DDIM; dst = Abf + (size_t)r * DDIM; nrm = xsq + r; }
    else             { r = row - NROWS; src = mem + (size_t)r * DDIM; dst = Bbf + (size_t)r * DDIM; nrm = msq + r; }
    unsigned scc = cc ^ ((r >> 1) & 3u);
    const float4* s4 = (const float4*)(src + seg * 32 + scc * 8);
    float4 a = s4[0], b = s4[1];
    ushort_t q[8];
    q[0]=f2bf(a.x); q[1]=f2bf(a.y); q[2]=f2bf(a.z); q[3]=f2bf(a.w);
    q[4]=f2bf(b.x); q[5]=f2bf(b.y); q[6]=f2bf(b.z); q[7]=f2bf(b.w);
    uint4 w;
    w.x = (uint_t)q[0] | ((uint_t)q[1] << 16);
    w.y = (uint_t)q[2] | ((uint_t)q[3] << 16);
    w.z = (uint_t)q[4] | ((uint_t)q[5] << 16);
    w.w = (uint_t)q[6] | ((uint_t)q[7] << 16);
    *(uint4*)(dst + seg * 32 + cc * 8) = w;
    float s = 0.f;
    #pragma unroll
    for (int i = 0; i < 8; ++i) { float v = bf2f(q[i]); s += v * v; }
    #pragma unroll
    for (int o = 1; o < 64; o <<= 1) s += __shfl_xor(s, o);
    if (lane == 0) *nrm = s;
}

// ---- main: 256x256 tile, 8 waves, BK=32, dbuf LDS, 2 phases/K-tile ----------
__global__ __launch_bounds__(512, 2) void gemm256_min(
    const ushort_t* __restrict__ Abf, const ushort_t* __restrict__ Bbf,
    const float* __restrict__ xsq, const float* __restrict__ msq,
    uint_t* __restrict__ minsq)
{
    __shared__ alignas(16) ushort_t As[2][BM * BKK];  // 2 x 16 KiB
    __shared__ alignas(16) ushort_t Bs[2][BN * BKK];  // 2 x 16 KiB

    const int tid  = threadIdx.x;
    const int lane = tid & 63;
    const int wave = tid >> 6;         // 0..7
    const int wm   = wave >> 2;        // 0..1  -> row half
    const int wn   = wave & 3;         // 0..3  -> col quarter
    const int laneRow = lane & 15;
    const int laneK   = lane >> 4;     // 0..3

    // bijective XCD-chunked swizzle (1024 % 8 == 0)
    unsigned wg  = blockIdx.x;
    unsigned swz = (wg & 7u) * (GRID_X / 8) + (wg >> 3);
    const unsigned rt = swz & 31u;     // 32 row tiles
    const unsigned cg = swz >> 5;      // 32 col groups
    const size_t r0    = (size_t)rt * BM;
    const size_t cbase = (size_t)cg * (BN * CT);

    // ds_read byte offsets within one 16-KiB tile buffer (row = 64 B)
    const int chunk = ((laneK ^ ((laneRow >> 1) & 3)) << 4);
    int offA[8], offB[4];
    #pragma unroll
    for (int m = 0; m < 8; ++m) offA[m] = (wm * 128 + m * 16 + laneRow) * 64 + chunk;
    #pragma unroll
    for (int n = 0; n < 4; ++n) offB[n] = (wn * 64 + n * 16 + laneRow) * 64 + chunk;

    // staging geometry: statement i covers rows i*128 + wave*16 + (lane>>2)
    const int rowoff = wave * 16 + (lane >> 2);
    const int inrow  = (lane & 3) * 16;
    const char* Ag = (const char*)Abf + (r0 + rowoff) * 1024 + inrow;

    f32x4 acc[8][4];
    float runmin[8][4];
    #pragma unroll
    for (int m = 0; m < 8; ++m)
        #pragma unroll
        for (int n = 0; n < 4; ++n) { acc[m][n] = (f32x4)0.f; runmin[m][n] = 3.0e38f; }

    // ---- prologue: stage K-tile 0 into buf 0, drain, barrier ----
    {
        const char* Asrc = Ag;  // ks=0
        const char* Bsrc = (const char*)Bbf + (cbase + rowoff) * 1024 + inrow;
        char* Ad = (char*)&As[0][0] + wave * 1024;
        char* Bd = (char*)&Bs[0][0] + wave * 1024;
        gll16(Asrc, Ad);                     gll16(Bsrc, Bd);
        gll16(Asrc + 131072, Ad + 8192);     gll16(Bsrc + 131072, Bd + 8192);
        asm volatile("s_waitcnt vmcnt(0)" ::: "memory");
        SCHED0(); SBAR(); SCHED0();
    }

    for (int t = 0; t < NT; ++t) {
        const int cur = t & 1;
        const char* AbC = (const char*)&As[cur][0];
        const char* BbC = (const char*)&Bs[cur][0];
        const bool stg = (t + 1) < NT;
        const char* AsrcN = nullptr; const char* BsrcN = nullptr;
        char* AdN = nullptr; char* BdN = nullptr;
        if (stg) {
            int t2 = t + 1;
            int ks2 = t2 & 15, ct2 = t2 >> 4;
            AsrcN = Ag + (size_t)ks2 * 64;
            BsrcN = (const char*)Bbf + (cbase + (size_t)ct2 * BN + rowoff) * 1024 + inrow + (size_t)ks2 * 64;
            AdN = (char*)&As[cur ^ 1][0] + wave * 1024;
            BdN = (char*)&Bs[cur ^ 1][0] + wave * 1024;
        }

        // ---------------- phase 0: m = 0..3 ----------------
        short8 af[4], bfr[4];
        #pragma unroll
        for (int m = 0; m < 4; ++m) af[m]  = *(const short8*)(AbC + offA[m]);
        #pragma unroll
        for (int n = 0; n < 4; ++n) bfr[n] = *(const short8*)(BbC + offB[n]);
        if (stg) { gll16(AsrcN, AdN); gll16(BsrcN, BdN); }
        SCHED0(); SBAR(); SCHED0();
        asm volatile("s_waitcnt lgkmcnt(0)" ::: "memory");
        SCHED0();
        __builtin_amdgcn_s_setprio(1);
        #pragma unroll
        for (int m = 0; m < 4; ++m)
            #pragma unroll
            for (int n = 0; n < 4; ++n)
                acc[m][n] = __builtin_amdgcn_mfma_f32_16x16x32_bf16(af[m], bfr[n], acc[m][n], 0, 0, 0);
        __builtin_amdgcn_s_setprio(0);
        SCHED0(); SBAR(); SCHED0();

        // ---------------- phase 1: m = 4..7 ----------------
        short8 ag[4];
        #pragma unroll
        for (int m = 0; m < 4; ++m) ag[m] = *(const short8*)(AbC + offA[m + 4]);
        if (stg) { gll16(AsrcN + 131072, AdN + 8192); gll16(BsrcN + 131072, BdN + 8192); }
        SCHED0(); SBAR(); SCHED0();
        asm volatile("s_waitcnt lgkmcnt(0)" ::: "memory");
        SCHED0();
        __builtin_amdgcn_s_setprio(1);
        #pragma unroll
        for (int m = 0; m < 4; ++m)
            #pragma unroll
            for (int n = 0; n < 4; ++n)
                acc[m + 4][n] = __builtin_amdgcn_mfma_f32_16x16x32_bf16(ag[m], bfr[n], acc[m + 4][n], 0, 0, 0);
        __builtin_amdgcn_s_setprio(0);
        SCHED0();
        // drain next tile's loads AFTER this phase's MFMA (issue->wait ~2 phases)
        asm volatile("s_waitcnt vmcnt(0)" ::: "memory");
        SCHED0(); SBAR(); SCHED0();

        // ---- end of a col-tile: fold acc into running min, reset acc ----
        if ((t & 15) == 15) {
            const size_t c0 = cbase + (size_t)(t >> 4) * BN;
            float mc[4];
            #pragma unroll
            for (int n = 0; n < 4; ++n) mc[n] = msq[c0 + wn * 64 + n * 16 + laneRow];
            #pragma unroll
            for (int m = 0; m < 8; ++m)
                #pragma unroll
                for (int n = 0; n < 4; ++n) {
                    #pragma unroll
                    for (int j = 0; j < 4; ++j)
                        runmin[m][j] = fminf(runmin[m][j], fmaf(-2.f, acc[m][n][j], mc[n]));
                    acc[m][n] = (f32x4)0.f;
                }
        }
    }

    // ---- epilogue: reduce over 16 col-lanes, add row norm, atomicMin ----
    #pragma unroll
    for (int m = 0; m < 8; ++m)
        #pragma unroll
        for (int j = 0; j < 4; ++j) {
            float v = runmin[m][j];
            v = fminf(v, __shfl_xor(v, 1));
            v = fminf(v, __shfl_xor(v, 2));
            v = fminf(v, __shfl_xor(v, 4));
            v = fminf(v, __shfl_xor(v, 8));
            if ((lane & 15) == 0) {
                int grow = (int)r0 + wm * 128 + m * 16 + laneK * 4 + j;
                float d2 = fmaxf(v + xsq[grow], 0.f);
                atomicMin(&minsq[grow], __float_as_uint(d2));
            }
        }
}

// ---- final sqrt --------------------------------------------------------------
__global__ void finish_kernel(const uint_t* __restrict__ minsq, float* __restrict__ out) {
    int i = blockIdx.x * 256 + threadIdx.x;
    if (i < NROWS) out[i] = sqrtf(__uint_as_float(minsq[i]));
}

// ======================= fallback path (ws too small) ========================
// Round-1-verified structure: 128x128 tile, 4 waves, BK=64, reg-staged fp32->bf16.
__global__ void norms_kernel(const float* __restrict__ emb, const float* __restrict__ mem,
                             float* __restrict__ xsq, float* __restrict__ msq) {
    int row  = blockIdx.x * 4 + (threadIdx.x >> 6);
    int lane = threadIdx.x & 63;
    const float* src; float* dst;
    if (row < NROWS) { src = emb + (size_t)row * DDIM;           dst = xsq + row; }
    else             { src = mem + (size_t)(row - NROWS) * DDIM; dst = msq + (row - NROWS); }
    float4 f0 = *(const float4*)(src + lane * 8);
    float4 f1 = *(const float4*)(src + lane * 8 + 4);
    float s = 0.f, v;
    v = bf2f(f2bf(f0.x)); s += v*v;  v = bf2f(f2bf(f0.y)); s += v*v;
    v = bf2f(f2bf(f0.z)); s += v*v;  v = bf2f(f2bf(f0.w)); s += v*v;
    v = bf2f(f2bf(f1.x)); s += v*v;  v = bf2f(f2bf(f1.y)); s += v*v;
    v = bf2f(f2bf(f1.z)); s += v*v;  v = bf2f(f2bf(f1.w)); s += v*v;
    #pragma unroll
    for (int o = 1; o < 64; o <<= 1) s += __shfl_xor(s, o);
    if (lane == 0) *dst = s;
}

__device__ __forceinline__ void fb_stage_load(const float* __restrict__ emb,
                                              const float* __restrict__ mem,
                                              size_t r0, size_t c0, int ks,
                                              float4* ra, float4* rb, int tid) {
    #pragma unroll
    for (int p = 0; p < 4; ++p) {
        int row = p * 32 + (tid >> 3);
        int c   = (tid & 7) * 8;
        const float* sa = emb + (r0 + row) * DDIM + ks * 64 + c;
        const float* sb = mem + (c0 + row) * DDIM + ks * 64 + c;
        ra[2*p]   = *(const float4*)sa;  ra[2*p+1] = *(const float4*)(sa + 4);
        rb[2*p]   = *(const float4*)sb;  rb[2*p+1] = *(const float4*)(sb + 4);
    }
}
__device__ __forceinline__ void fb_stage_write(ushort_t* Ab, ushort_t* Bb,
                                               const float4* ra, const float4* rb, int tid) {
    #pragma unroll
    for (int p = 0; p < 4; ++p) {
        int row = p * 32 + (tid >> 3);
        int ccs = (tid & 7) ^ (row & 7);
        uint4 wa, wb;
        wa.x = (uint_t)f2bf(ra[2*p].x)   | ((uint_t)f2bf(ra[2*p].y)   << 16);
        wa.y = (uint_t)f2bf(ra[2*p].z)   | ((uint_t)f2bf(ra[2*p].w)   << 16);
        wa.z = (uint_t)f2bf(ra[2*p+1].x) | ((uint_t)f2bf(ra[2*p+1].y) << 16);
        wa.w = (uint_t)f2bf(ra[2*p+1].z) | ((uint_t)f2bf(ra[2*p+1].w) << 16);
        wb.x = (uint_t)f2bf(rb[2*p].x)   | ((uint_t)f2bf(rb[2*p].y)   << 16);
        wb.y = (uint_t)f2bf(rb[2*p].z)   | ((uint_t)f2bf(rb[2*p].w)   << 16);
        wb.z = (uint_t)f2bf(rb[2*p+1].x) | ((uint_t)f2bf(rb[2*p+1].y) << 16);
        wb.w = (uint_t)f2bf(rb[2*p+1].z) | ((uint_t)f2bf(rb[2*p+1].w) << 16);
        *(uint4*)&Ab[row * 64 + ccs * 8] = wa;
        *(uint4*)&Bb[row * 64 + ccs * 8] = wb;
    }
}

__global__ __launch_bounds__(256, 2) void gemm_min_fb(
    const float* __restrict__ emb, const float* __restrict__ mem,
    const float* __restrict__ xsq, const float* __restrict__ msq,
    uint_t* __restrict__ minsq)
{
    __shared__ alignas(16) ushort_t Ab[128 * 64];
    __shared__ alignas(16) ushort_t Bb[128 * 64];
    const int tid = threadIdx.x, lane = tid & 63, wave = tid >> 6;
    const int wm = wave >> 1, wn = wave & 1;
    unsigned wg = blockIdx.x;
    unsigned swz = (wg & 7u) * (2048 / 8) + (wg >> 3);
    const unsigned rt = swz & 63u, cgf = swz >> 6;
    const size_t r0 = (size_t)rt * 128;
    float runmin[4][4];
    #pragma unroll
    for (int m = 0; m < 4; ++m)
        #pragma unroll
        for (int j = 0; j < 4; ++j) runmin[m][j] = 3.0e38f;
    float4 ra[8], rb[8];
    for (int ctf = 0; ctf < 16; ++ctf) {
        const size_t c0 = ((size_t)cgf * 16 + ctf) * 128;
        f32x4 acc[4][4] = {};
        fb_stage_load(emb, mem, r0, c0, 0, ra, rb, tid);
        for (int ks = 0; ks < 8; ++ks) {
            __syncthreads();
            fb_stage_write(Ab, Bb, ra, rb, tid);
            if (ks + 1 < 8) fb_stage_load(emb, mem, r0, c0, ks + 1, ra, rb, tid);
            __syncthreads();
            #pragma unroll
            for (int kk = 0; kk < 2; ++kk) {
                short8 af[4], bfm[4];
                #pragma unroll
                for (int m = 0; m < 4; ++m) {
                    int r = wm * 64 + m * 16 + (lane & 15);
                    int c = ((kk * 4 + (lane >> 4)) ^ (r & 7)) * 8;
                    af[m] = *(const short8*)&Ab[r * 64 + c];
                }
                #pragma unroll
                for (int n = 0; n < 4; ++n) {
                    int r = wn * 64 + n * 16 + (lane & 15);
                    int c = ((kk * 4 + (lane >> 4)) ^ (r & 7)) * 8;
                    bfm[n] = *(const short8*)&Bb[r * 64 + c];
                }
                #pragma unroll
                for (int m = 0; m < 4; ++m)
                    #pragma unroll
                    for (int n = 0; n < 4; ++n)
                        acc[m][n] = __builtin_amdgcn_mfma_f32_16x16x32_bf16(af[m], bfm[n], acc[m][n], 0, 0, 0);
            }
        }
        float mc[4];
        #pragma unroll
        for (int n = 0; n < 4; ++n) mc[n] = msq[c0 + wn * 64 + n * 16 + (lane & 15)];
        #pragma unroll
        for (int m = 0; m < 4; ++m)
            #pragma unroll
            for (int n = 0; n < 4; ++n)
                #pragma unroll
                for (int j = 0; j < 4; ++j)
                    runmin[m][j] = fminf(runmin[m][j], fmaf(-2.f, acc[m][n][j], mc[n]));
    }
    #pragma unroll
    for (int m = 0; m < 4; ++m)
        #pragma unroll
        for (int j = 0; j < 4; ++j) {
            float v = runmin[m][j];
            v = fminf(v, __shfl_xor(v, 1));
            v = fminf(v, __shfl_xor(v, 2));
            v = fminf(v, __shfl_xor(v, 4));
            v = fminf(v, __shfl_xor(v, 8));
            if ((lane & 15) == 0) {
                int grow = (int)r0 + wm * 64 + m * 16 + (lane >> 4) * 4 + j;
                float d2 = fmaxf(v + xsq[grow], 0.f);
                atomicMin(&minsq[grow], __float_as_uint(d2));
            }
        }
}

extern "C" void kernel_launch(void* const* d_in, const int* in_sizes, int n_in,
                              void* d_out, int out_size, void* d_ws, size_t ws_size,
                              hipStream_t stream) {
    const float* emb = (const float*)d_in[0];
    const float* mem = (const float*)d_in[1];
    float* out = (float*)d_out;

    char* ws = (char*)d_ws;
    float*  xsq   = (float*)ws;                          // 32 KiB
    float*  msq   = (float*)(ws + 32768);                // 256 KiB
    uint_t* minsq = (uint_t*)(ws + 32768 + 262144);      // 32 KiB
    ushort_t* Abf = (ushort_t*)(ws + 327680);            // 8 MiB
    ushort_t* Bbf = Abf + (size_t)NROWS * DDIM;          // 64 MiB
    const size_t NEED = 327680 + ((size_t)NROWS + MROWS) * DDIM * 2;

    init_minsq<<<(NROWS + 255) / 256, 256, 0, stream>>>(minsq);
    if (ws_size >= NEED) {
        convert_norms<<<((NROWS + MROWS) * 64) / 256, 256, 0, stream>>>(emb, mem, Abf, Bbf, xsq, msq);
        gemm256_min<<<GRID_X, 512, 0, stream>>>(Abf, Bbf, xsq, msq, minsq);
    } else {
        norms_kernel<<<(NROWS + MROWS) / 4, 256, 0, stream>>>(emb, mem, xsq, msq);
        gemm_min_fb<<<2048, 256, 0, stream>>>(emb, mem, xsq, msq, minsq);
    }
    finish_kernel<<<(NROWS + 255) / 256, 256, 0, stream>>>(minsq, out);
}